// Round 10
// baseline (301.611 us; speedup 1.0000x reference)
//
#include <hip/hip_runtime.h>
#include <hip/hip_fp16.h>
#include <math.h>

#define DIN   32
#define F1    64   // H1*C1
#define F2    64   // H2*C2

// packed-f32 pair: maps to v_pk_fma_f32 / v_pk_add_f32 / v_pk_mul_f32 on gfx950
typedef __attribute__((ext_vector_type(2))) float f32x2;

__device__ __forceinline__ f32x2 pkfma(f32x2 a, f32x2 b, f32x2 c) {
#if __has_builtin(__builtin_elementwise_fma)
    return __builtin_elementwise_fma(a, b, c);
#else
    return a * b + c;
#endif
}
__device__ __forceinline__ f32x2 pkmax(f32x2 a, f32x2 b) {
    f32x2 r; r.x = fmaxf(a.x, b.x); r.y = fmaxf(a.y, b.y); return r;
}

// bf16 round-to-nearest-even pack of two floats into one uint
__device__ __forceinline__ unsigned bf16pack(float a, float b) {
    unsigned ua = __float_as_uint(a);
    unsigned ub = __float_as_uint(b);
    ua = (ua + 0x7FFFu + ((ua >> 16) & 1u)) >> 16;
    ub = (ub + 0x7FFFu + ((ub >> 16) & 1u)) >> 16;
    return ua | (ub << 16);
}

// ---------------- dense-linear body (shared) --------------------------------
// 32-node x 128-output tile, 256 threads, 2x8 micro-tile.
// xl output stored FP16 (halves the gat gather bytes); xr stays FP32.
template <int K>
__device__ __forceinline__ void lin_lr_body(int bid,
        const float* __restrict__ x,
        const float* __restrict__ Wl, const float* __restrict__ bl,
        const float* __restrict__ Wr, const float* __restrict__ br,
        __half* __restrict__ xl, float* __restrict__ xr, int n) {
    __shared__ float Ash[32][K + 4];
    __shared__ float Wsh[K][128];
    const int t = threadIdx.x;
    const int node0 = bid * 32;

    for (int idx = t; idx < 32 * (K / 4); idx += 256) {
        int m = idx / (K / 4), kq = idx % (K / 4);
        float4 v = make_float4(0.f, 0.f, 0.f, 0.f);
        if (node0 + m < n) v = ((const float4*)(x + (size_t)(node0 + m) * K))[kq];
        *(float4*)&Ash[m][kq * 4] = v;
    }
    for (int idx = t; idx < K * 32; idx += 256) {
        int k = idx / 32, j4 = idx % 32;
        float4 v = (j4 < 16) ? ((const float4*)(Wl + (size_t)k * 64))[j4]
                             : ((const float4*)(Wr + (size_t)k * 64))[j4 - 16];
        *(float4*)&Wsh[k][j4 * 4] = v;
    }
    __syncthreads();

    const int ty = t >> 4;
    const int tx = t & 15;
    f32x2 c0[4], c1[4];
#pragma unroll
    for (int j = 0; j < 4; j++) {
        c0[j].x = 0.f; c0[j].y = 0.f;
        c1[j].x = 0.f; c1[j].y = 0.f;
    }

#pragma unroll 4
    for (int k = 0; k < K; k++) {
        float a0 = Ash[ty * 2 + 0][k];
        float a1 = Ash[ty * 2 + 1][k];
        float4 w0 = *(const float4*)&Wsh[k][tx * 8];
        float4 w1 = *(const float4*)&Wsh[k][tx * 8 + 4];
        f32x2 wv0; wv0.x = w0.x; wv0.y = w0.y;
        f32x2 wv1; wv1.x = w0.z; wv1.y = w0.w;
        f32x2 wv2; wv2.x = w1.x; wv2.y = w1.y;
        f32x2 wv3; wv3.x = w1.z; wv3.y = w1.w;
        f32x2 a0s; a0s.x = a0; a0s.y = a0;
        f32x2 a1s; a1s.x = a1; a1s.y = a1;
        c0[0] = pkfma(a0s, wv0, c0[0]);
        c0[1] = pkfma(a0s, wv1, c0[1]);
        c0[2] = pkfma(a0s, wv2, c0[2]);
        c0[3] = pkfma(a0s, wv3, c0[3]);
        c1[0] = pkfma(a1s, wv0, c1[0]);
        c1[1] = pkfma(a1s, wv1, c1[1]);
        c1[2] = pkfma(a1s, wv2, c1[2]);
        c1[3] = pkfma(a1s, wv3, c1[3]);
    }

    const float* bsrc = (tx < 8) ? bl : br;
    int jb = (tx < 8) ? tx * 8 : (tx - 8) * 8;
    float4 b0 = ((const float4*)(bsrc + jb))[0];
    float4 b1 = ((const float4*)(bsrc + jb))[1];
#pragma unroll
    for (int m = 0; m < 2; m++) {
        int node = node0 + ty * 2 + m;
        if (node >= n) continue;
        const f32x2* cc = (m == 0) ? c0 : c1;
        float o0 = cc[0].x + b0.x, o1 = cc[0].y + b0.y;
        float o2 = cc[1].x + b0.z, o3 = cc[1].y + b0.w;
        float o4 = cc[2].x + b1.x, o5 = cc[2].y + b1.y;
        float o6 = cc[3].x + b1.z, o7 = cc[3].y + b1.w;
        if (tx < 8) {
            __half2 h0 = __floats2half2_rn(o0, o1);
            __half2 h1 = __floats2half2_rn(o2, o3);
            __half2 h2 = __floats2half2_rn(o4, o5);
            __half2 h3 = __floats2half2_rn(o6, o7);
            uint4 pk;
            pk.x = *(unsigned*)&h0; pk.y = *(unsigned*)&h1;
            pk.z = *(unsigned*)&h2; pk.w = *(unsigned*)&h3;
            *((uint4*)(xl + (size_t)node * 64 + jb)) = pk;
        } else {
            float4 f0 = make_float4(o0, o1, o2, o3);
            float4 f1 = make_float4(o4, o5, o6, o7);
            ((float4*)(xr + (size_t)node * 64 + jb))[0] = f0;
            ((float4*)(xr + (size_t)node * 64 + jb))[1] = f1;
        }
    }
}

// ---------------- K1: count + rank + scatter, single global read ------------
// One pass over {src,dst,ea}; records staged in LDS (rec, rank, bucket),
// then scattered straight from LDS after the cursor reserve. Per-edge
// atomics stay in LDS (R4: global per-edge atomics cost ~77 us).
// R10: NCH 512 -> 1024 (Ec ~1563): LDS drops ~40 KB -> ~22 KB, so 4 blocks
// /CU (32 waves, full occupancy) instead of 2 — twice the TLP to hide the
// LDS-atomic + scattered-write latency. Record flow identical to R8.
__global__ __launch_bounds__(512, 2)
void count_scatter(const int* __restrict__ srcr, const int* __restrict__ dstr,
                   const float* __restrict__ ea, int* __restrict__ cursor,
                   int2* __restrict__ inter, int E, int Ec, int NB, int cap) {
    __shared__ int2 recsh[1792];
    __shared__ unsigned short rksh[1792];
    __shared__ unsigned char bksh[1792];
    __shared__ int hist[256];
    __shared__ int colsh[256];
    const int blk = blockIdx.x;
    const int t = threadIdx.x;
    if (t < 256) hist[t] = 0;
    __syncthreads();
    const int s0 = blk * Ec, s1 = min(E, s0 + Ec);
    const int cnt = s1 - s0;
    for (int e = s0 + t; e < s1; e += 512) {
        int d = dstr[e];
        float2 v = ((const float2*)ea)[e];
        int2 r;
        r.x = srcr[e] | ((d & 255) << 24);
        r.y = (int)bf16pack(v.x, v.y);
        int li = e - s0;
        int bk = (unsigned)d >> 8;
        recsh[li] = r;
        bksh[li] = (unsigned char)bk;
        rksh[li] = (unsigned short)atomicAdd(&hist[bk], 1);
    }
    __syncthreads();
    if (t < NB) {
        int h = hist[t];
        colsh[t] = t * cap + (h ? atomicAdd(&cursor[t], h) : 0);
    }
    __syncthreads();
    for (int li = t; li < cnt; li += 512)
        inter[colsh[bksh[li]] + (int)rksh[li]] = recsh[li];
}

// ---------------- K2: per-bucket CSR finalize || lin1 -----------------------
// csr has only NB=196 blocks on 256 CUs; lin1 (no dependency on the CSR)
// fills the idle CUs so K2 costs ~max(csr, lin1) instead of csr + lin1.
__global__ __launch_bounds__(256, 2)
void fused_csr_lin1(const int2* __restrict__ inter, const int* __restrict__ cursor,
                    int2* __restrict__ rse, int2* __restrict__ edges,
                    int NB, int N, int cap,
                    const float* __restrict__ x,
                    const float* __restrict__ Wl, const float* __restrict__ bl,
                    const float* __restrict__ Wr, const float* __restrict__ br,
                    __half* __restrict__ xl, float* __restrict__ xr, int n) {
    if ((int)blockIdx.x >= NB) {
        lin_lr_body<DIN>(blockIdx.x - NB, x, Wl, bl, Wr, br, xl, xr, n);
        return;
    }
    __shared__ int sh[256];
    __shared__ int cur[256];
    const int b = blockIdx.x, t = threadIdx.x;
    const int bstart = b * cap;
    const int bend = bstart + cursor[b];

    sh[t] = 0;
    __syncthreads();
    for (int pos = bstart + t; pos < bend; pos += 256)
        atomicAdd(&sh[((unsigned)inter[pos].x) >> 24], 1);
    __syncthreads();
    int cnt_v = sh[t];
    __syncthreads();
    sh[t] = cnt_v;
    __syncthreads();
    for (int off = 1; off < 256; off <<= 1) {
        int xv = (t >= off) ? sh[t - off] : 0;
        __syncthreads();
        sh[t] += xv;
        __syncthreads();
    }
    {
        int excl = sh[t] - cnt_v;
        cur[t] = excl;
        int myrs = bstart + excl;
        int node = b * 256 + t;
        if (node < N) rse[node] = make_int2(myrs, myrs + cnt_v);
    }
    __syncthreads();
    for (int pos = bstart + t; pos < bend; pos += 256) {
        int2 r = inter[pos];
        int k = atomicAdd(&cur[((unsigned)r.x) >> 24], 1);
        r.x &= 0x00FFFFFF;                      // strip dst byte for gat
        edges[bstart + k] = r;
    }
    // zero the gap so gat prefetches past rse[] read {src=0, ea=0} records
    int zend = (b + 1) * cap + ((b == NB - 1) ? 64 : 0);
    for (int pos = bend + t; pos < zend; pos += 256)
        edges[pos] = make_int2(0, 0);
}

// ---------------- GATv2 edge phase (unchanged from R8) ----------------------
// R0/R1 loop structure: full 128-B row gather, 8 edges/iter, 1-deep
// pipeline, packed f32 math, inline self-loop mean. FUSE_LIN2: W2 staged in
// LDS once per 512-thr block, h broadcast via v_readlane.
template <int H, int C, bool FUSE_HEADS, bool FUSE_LIN2>
__global__ __launch_bounds__(512)
void gat_kernel(const __half* __restrict__ xl, const float* __restrict__ xr,
                const int2* __restrict__ rse,
                const int2* __restrict__ edges,
                const float* __restrict__ We, const float* __restrict__ att,
                const float* __restrict__ bias, float* __restrict__ hout,
                const float* __restrict__ w2l, const float* __restrict__ b2l,
                const float* __restrict__ w2r, const float* __restrict__ b2r,
                __half* __restrict__ xl2o, float* __restrict__ xr2o,
                const float* __restrict__ wa, const float* __restrict__ ba,
                const float* __restrict__ wc, const float* __restrict__ bc,
                const float* __restrict__ ls, float* __restrict__ pout,
                int n) {
    constexpr int LPH = C / 4;
    __shared__ float W2sh[FUSE_LIN2 ? 64 * 128 : 4];
    if constexpr (FUSE_LIN2) {
        // stage W2 (cols 0-63 = w2l, 64-127 = w2r) before any wave returns
        for (int idx = threadIdx.x; idx < 64 * 32; idx += (int)blockDim.x) {
            int k = idx >> 5, j4 = idx & 31;
            float4 v = (j4 < 16) ? ((const float4*)(w2l + (size_t)k * 64))[j4]
                                 : ((const float4*)(w2r + (size_t)k * 64))[j4 - 16];
            *(float4*)&W2sh[k * 128 + j4 * 4] = v;
        }
        __syncthreads();
    }
    if (FUSE_HEADS && blockIdx.x == 0 && threadIdx.x < 2)
        pout[(size_t)n * 2 + threadIdx.x] = expf(ls[threadIdx.x]);
    const int lane = threadIdx.x & 63;
    const int wid = (blockIdx.x * blockDim.x + threadIdx.x) >> 6;
    if (wid >= n) return;
    const int i = wid;
    const int g = lane >> 4;
    const int q = lane & 15;

    const uint2* xlh = (const uint2*)xl;      // 4 halfs per uint2; row = 16
    const float4 xri4 = ((const float4*)(xr + (size_t)i * 64))[q];
    const float4 we04 = ((const float4*)We)[q];
    const float4 we14 = ((const float4*)(We + 64))[q];
    const float4 av4 = ((const float4*)att)[q];
    const float LOG2E = 1.4426950408889634f;
    f32x2 xrlo; xrlo.x = xri4.x; xrlo.y = xri4.y;
    f32x2 xrhi; xrhi.x = xri4.z; xrhi.y = xri4.w;
    f32x2 we0lo; we0lo.x = we04.x; we0lo.y = we04.y;
    f32x2 we0hi; we0hi.x = we04.z; we0hi.y = we04.w;
    f32x2 we1lo; we1lo.x = we14.x; we1lo.y = we14.y;
    f32x2 we1hi; we1hi.x = we14.z; we1hi.y = we14.w;
    f32x2 avlo; avlo.x = av4.x * LOG2E; avlo.y = av4.y * LOG2E;
    f32x2 avhi; avhi.x = av4.z * LOG2E; avhi.y = av4.w * LOG2E;

    auto h4lo = [](uint2 h) -> f32x2 {
        float2 a = __half22float2(*(__half2*)&h.x);
        f32x2 r; r.x = a.x; r.y = a.y; return r;
    };
    auto h4hi = [](uint2 h) -> f32x2 {
        float2 b = __half22float2(*(__half2*)&h.y);
        f32x2 r; r.x = b.x; r.y = b.y; return r;
    };
    // leaky_relu(xh + ea0*we0 + ea1*we1 + xri) . att   (att pre-scaled LOG2E)
    auto logit_of = [&](f32x2 xlo, f32x2 xhi, float ea0, float ea1) -> float {
        f32x2 e0; e0.x = ea0; e0.y = ea0;
        f32x2 e1; e1.x = ea1; e1.y = ea1;
        f32x2 ylo = xlo + pkfma(e0, we0lo, pkfma(e1, we1lo, xrlo));
        f32x2 yhi = xhi + pkfma(e0, we0hi, pkfma(e1, we1hi, xrhi));
        ylo = pkmax(ylo, ylo * 0.2f);
        yhi = pkmax(yhi, yhi * 0.2f);
        f32x2 l2 = pkfma(ylo, avlo, yhi * avhi);
        return l2.x + l2.y;
    };

    float den = 0.f;
    float sea0 = 0.f, sea1 = 0.f;   // inline ea sums for self-loop mean
    f32x2 aclo; aclo.x = 0.f; aclo.y = 0.f;
    f32x2 achi; achi.x = 0.f; achi.y = 0.f;

    const int2 se = rse[i];
    const int e0 = se.x, e1 = se.y;
    const int r = (e1 - e0) & 7;

    // ---- masked head: the (deg mod 8) ragged edges, done FIRST ----
    if (r) {
        int2 h0 = edges[e0 + g];
        int2 h1 = edges[e0 + 4 + g];
        uint2 u0 = xlh[(h0.x << 4) + q];
        uint2 u1 = xlh[(h1.x << 4) + q];
        f32x2 x0lo = h4lo(u0), x0hi = h4hi(u0);
        f32x2 x1lo = h4lo(u1), x1hi = h4hi(u1);
        const bool v0 = g < r;
        const bool v1 = (4 + g) < r;
        float ea00 = v0 ? __int_as_float(h0.y << 16) : 0.f;
        float ea01 = v0 ? __int_as_float(h0.y & 0xFFFF0000) : 0.f;
        float ea10 = v1 ? __int_as_float(h1.y << 16) : 0.f;
        float ea11 = v1 ? __int_as_float(h1.y & 0xFFFF0000) : 0.f;
        sea0 += ea00 + ea10;
        sea1 += ea01 + ea11;
        float l0 = logit_of(x0lo, x0hi, ea00, ea01);
        float l1 = logit_of(x1lo, x1hi, ea10, ea11);
#pragma unroll
        for (int m = 1; m < LPH; m <<= 1) {
            l0 += __shfl_xor(l0, m, 64);
            l1 += __shfl_xor(l1, m, 64);
        }
        float p0 = v0 ? exp2f(l0) : 0.f;
        float p1 = v1 ? exp2f(l1) : 0.f;
        den += p0 + p1;
        f32x2 p0s; p0s.x = p0; p0s.y = p0;
        f32x2 p1s; p1s.x = p1; p1s.y = p1;
        aclo = pkfma(p0s, x0lo, pkfma(p1s, x1lo, aclo));
        achi = pkfma(p0s, x0hi, pkfma(p1s, x1hi, achi));
    }

    // ---- mask-free main loop (multiple of 8 edges), 1-deep pipeline ----
    const int em = e0 + r;
    int2 rn0 = edges[em + g];
    int2 rn1 = edges[em + 4 + g];
    uint2 xpn0 = xlh[(rn0.x << 4) + q];
    uint2 xpn1 = xlh[(rn1.x << 4) + q];

    for (int eb = em; eb < e1; eb += 8) {
        int2 r0 = rn0, r1 = rn1;
        f32x2 x0lo = h4lo(xpn0), x0hi = h4hi(xpn0);
        f32x2 x1lo = h4lo(xpn1), x1hi = h4hi(xpn1);
        rn0 = edges[eb + 8 + g];
        rn1 = edges[eb + 12 + g];
        xpn0 = xlh[(rn0.x << 4) + q];
        xpn1 = xlh[(rn1.x << 4) + q];

        float ea00 = __int_as_float(r0.y << 16);
        float ea01 = __int_as_float(r0.y & 0xFFFF0000);
        float ea10 = __int_as_float(r1.y << 16);
        float ea11 = __int_as_float(r1.y & 0xFFFF0000);
        sea0 += ea00 + ea10;
        sea1 += ea01 + ea11;

        float l0 = logit_of(x0lo, x0hi, ea00, ea01);
        float l1 = logit_of(x1lo, x1hi, ea10, ea11);
#pragma unroll
        for (int m = 1; m < LPH; m <<= 1) {
            l0 += __shfl_xor(l0, m, 64);
            l1 += __shfl_xor(l1, m, 64);
        }
        float p0 = exp2f(l0);
        float p1 = exp2f(l1);
        den += p0 + p1;
        f32x2 p0s; p0s.x = p0; p0s.y = p0;
        f32x2 p1s; p1s.x = p1; p1s.y = p1;
        aclo = pkfma(p0s, x0lo, pkfma(p1s, x1lo, aclo));
        achi = pkfma(p0s, x0hi, pkfma(p1s, x1hi, achi));
    }

    float a0 = aclo.x, a1 = aclo.y, a2 = achi.x, a3 = achi.y;

    // merge the 4 edge-slot groups — pure adds (sea folded in here too)
#pragma unroll
    for (int m = 16; m < 64; m <<= 1) {
        den += __shfl_xor(den, m, 64);
        a0 += __shfl_xor(a0, m, 64);
        a1 += __shfl_xor(a1, m, 64);
        a2 += __shfl_xor(a2, m, 64);
        a3 += __shfl_xor(a3, m, 64);
        sea0 += __shfl_xor(sea0, m, 64);
        sea1 += __shfl_xor(sea1, m, 64);
    }

    // self-loop: mean attr computed inline (deg = e1-e0; 0-deg -> 0 mean,
    // matching reference's sums/max(cnt,1))
    const int cnt_i = e1 - e0;
    const float invc = cnt_i ? 1.0f / (float)cnt_i : 0.f;
    const float lamx = sea0 * invc;
    const float lamy = sea1 * invc;
    uint2 us = xlh[(i << 4) + q];
    f32x2 xslo = h4lo(us), xshi = h4hi(us);
    {
        float l = logit_of(xslo, xshi, lamx, lamy);
#pragma unroll
        for (int m = 1; m < LPH; m <<= 1) l += __shfl_xor(l, m, 64);
        float p = exp2f(l);
        den += p;
        a0 = fmaf(p, xslo.x, a0);
        a1 = fmaf(p, xslo.y, a1);
        a2 = fmaf(p, xshi.x, a2);
        a3 = fmaf(p, xshi.y, a3);
    }

    float rd = 1.0f / den;
    const float4 bv = ((const float4*)bias)[q];
    float4 o;
    o.x = fmaxf(fmaf(a0, rd, bv.x), 0.f);
    o.y = fmaxf(fmaf(a1, rd, bv.y), 0.f);
    o.z = fmaxf(fmaf(a2, rd, bv.z), 0.f);
    o.w = fmaxf(fmaf(a3, rd, bv.w), 0.f);
    // o (= post-ReLU h-row fragment for features 4q..4q+3) is identical in
    // all 4 lane-groups: every input to it was group-invariant.

    if constexpr (FUSE_LIN2) {
        // lin2: out[j] = sum_k h[k]*W2[k][j] + b2[j]; lane owns cols 2*lane,
        // 2*lane+1 (cols<64 -> xl2 via w2l, cols>=64 -> xr2 via w2r).
        const int hl = lane & 31;
        const bool isl = lane < 32;
        f32x2 s; s.x = 0.f; s.y = 0.f;
#pragma unroll
        for (int k = 0; k < 64; k++) {
            float comp = ((k & 3) == 0) ? o.x : ((k & 3) == 1) ? o.y
                       : ((k & 3) == 2) ? o.z : o.w;
            float hk = __uint_as_float(
                __builtin_amdgcn_readlane(__float_as_uint(comp), k >> 2));
            f32x2 hs; hs.x = hk; hs.y = hk;
            f32x2 wv = *(const f32x2*)&W2sh[k * 128 + 2 * lane];
            s = pkfma(hs, wv, s);
        }
        const float* bsel = isl ? b2l : b2r;
        s.x += bsel[2 * hl];
        s.y += bsel[2 * hl + 1];
        if (isl) {
            __half2 hx = __floats2half2_rn(s.x, s.y);
            *(unsigned*)(xl2o + (size_t)i * 64 + 2 * hl) = *(unsigned*)&hx;
        } else {
            ((float2*)(xr2o + (size_t)i * 64))[hl] = make_float2(s.x, s.y);
        }
    } else if (!FUSE_HEADS) {
        if (g == 0) ((float4*)(hout + (size_t)i * 64))[q] = o;
    } else {
        float4 wa01 = ((const float4*)wa)[q * 2];
        float4 wa23 = ((const float4*)wa)[q * 2 + 1];
        float4 wcv  = ((const float4*)wc)[q];
        float d0 = o.x * wa01.x + o.y * wa01.z + o.z * wa23.x + o.w * wa23.z;
        float d1 = o.x * wa01.y + o.y * wa01.w + o.z * wa23.y + o.w * wa23.w;
        float d2 = o.x * wcv.x + o.y * wcv.y + o.z * wcv.z + o.w * wcv.w;
#pragma unroll
        for (int m = 1; m < 16; m <<= 1) {
            d0 += __shfl_xor(d0, m, 64);
            d1 += __shfl_xor(d1, m, 64);
            d2 += __shfl_xor(d2, m, 64);
        }
        if (lane == 0) {
            pout[(size_t)i * 2 + 0] = tanhf(d0 + ba[0]);
            pout[(size_t)i * 2 + 1] = tanhf(d1 + ba[1]);
            pout[(size_t)n * 2 + 2 + i] = d2 + bc[0];
        }
    }
}

// ---------------- launch ---------------------------------------------------

extern "C" void kernel_launch(void* const* d_in, const int* in_sizes, int n_in,
                              void* d_out, int out_size, void* d_ws, size_t ws_size,
                              hipStream_t stream) {
    const float* x    = (const float*)d_in[0];
    const int*   ei   = (const int*)  d_in[1];
    const float* ea   = (const float*)d_in[2];
    const float* w1l  = (const float*)d_in[3];
    const float* b1l  = (const float*)d_in[4];
    const float* w1r  = (const float*)d_in[5];
    const float* b1r  = (const float*)d_in[6];
    const float* w1e  = (const float*)d_in[7];
    const float* att1 = (const float*)d_in[8];
    const float* bias1= (const float*)d_in[9];
    const float* w2l  = (const float*)d_in[10];
    const float* b2l  = (const float*)d_in[11];
    const float* w2r  = (const float*)d_in[12];
    const float* b2r  = (const float*)d_in[13];
    const float* w2e  = (const float*)d_in[14];
    const float* att2 = (const float*)d_in[15];
    const float* bias2= (const float*)d_in[16];
    const float* wa   = (const float*)d_in[17];
    const float* ba   = (const float*)d_in[18];
    const float* wc   = (const float*)d_in[19];
    const float* bc   = (const float*)d_in[20];
    const float* ls   = (const float*)d_in[21];

    const int N = in_sizes[0] / DIN;
    const int E = in_sizes[2] / 2;
    const int* srcr = ei;
    const int* dstr = ei + E;

    const int NB = (N + 255) >> 8;           // node buckets (196)
    const int NCH = 1024;                    // edge chunks (rec LDS <= 1792)
    const int Ec = (E + NCH - 1) / NCH;      // edges per chunk (~1563)
    int cap = (E + NB - 1) / NB;             // bucket capacity, 1.25x mean
    cap = ((cap + cap / 4) + 63) & ~63;

    char* p = (char*)d_ws;
    auto alloc = [&](size_t bytes) -> void* {
        void* r = (void*)p;
        p += (bytes + 255) & ~(size_t)255;
        return r;
    };
    int*    cursor = (int*)   alloc(256 * 4);
    int2*   rse    = (int2*)  alloc((size_t)N * 8);
    int2*   edges  = (int2*)  alloc(((size_t)NB * cap + 64) * 8);
    __half* xl     = (__half*)alloc((size_t)N * F1 * 2);
    float*  xr     = (float*) alloc((size_t)N * F1 * 4);
    // layer-2 feature buffers (fused gat1+lin2 writes these; must NOT alias
    // xl/xr which gat1 is still gathering from)
    __half* xl2    = (__half*)alloc((size_t)N * F2 * 2);
    float*  xr2    = (float*) alloc((size_t)N * F2 * 4);
    // inter (NB*cap*8 ~= 16 MB) aliases xl2+xr2 (19.2 MB); consumed by the
    // csr blocks of fused_csr_lin1 before gat1 (which writes xl2/xr2) runs.
    int2* inter = (int2*)xl2;
    (void)ws_size; (void)n_in; (void)out_size;

    hipMemsetAsync(cursor, 0, 256 * 4, stream);

    const int TB = 256;
    int gridGemm = (N + 31) / 32;
    int gridW1 = (N + 7) / 8;       // gat1: 512-thr blocks, 8 nodes each
    int gridW2 = (N + 3) / 4;       // gat2: 256-thr blocks, 4 nodes each

    count_scatter<<<NCH, 512, 0, stream>>>(srcr, dstr, ea, cursor, inter,
                                           E, Ec, NB, cap);
    fused_csr_lin1<<<NB + gridGemm, TB, 0, stream>>>(
        inter, cursor, rse, edges, NB, N, cap,
        x, w1l, b1l, w1r, b1r, xl, xr, N);

    // gat layer 1 with lin2 fused into the epilogue (LDS-staged W2)
    gat_kernel<4, 16, false, true><<<gridW1, 512, 0, stream>>>(
        xl, xr, rse, edges, w1e, att1, bias1, nullptr,
        w2l, b2l, w2r, b2r, xl2, xr2,
        nullptr, nullptr, nullptr, nullptr, nullptr, nullptr, N);

    // gat layer 2 with actor/critic head fused
    gat_kernel<2, 32, true, false><<<gridW2, TB, 0, stream>>>(
        xl2, xr2, rse, edges, w2e, att2, bias2, nullptr,
        nullptr, nullptr, nullptr, nullptr, nullptr, nullptr,
        wa, ba, wc, bc, ls, (float*)d_out, N);
}

// Round 11
// 280.895 us; speedup vs baseline: 1.0737x; 1.0737x over previous
//
#include <hip/hip_runtime.h>
#include <hip/hip_fp16.h>
#include <math.h>

#define DIN   32
#define F1    64   // H1*C1
#define F2    64   // H2*C2

// packed-f32 pair: maps to v_pk_fma_f32 / v_pk_add_f32 / v_pk_mul_f32 on gfx950
typedef __attribute__((ext_vector_type(2))) float f32x2;

__device__ __forceinline__ f32x2 pkfma(f32x2 a, f32x2 b, f32x2 c) {
#if __has_builtin(__builtin_elementwise_fma)
    return __builtin_elementwise_fma(a, b, c);
#else
    return a * b + c;
#endif
}
__device__ __forceinline__ f32x2 pkmax(f32x2 a, f32x2 b) {
    f32x2 r; r.x = fmaxf(a.x, b.x); r.y = fmaxf(a.y, b.y); return r;
}

// bf16 round-to-nearest-even pack of two floats into one uint
__device__ __forceinline__ unsigned bf16pack(float a, float b) {
    unsigned ua = __float_as_uint(a);
    unsigned ub = __float_as_uint(b);
    ua = (ua + 0x7FFFu + ((ua >> 16) & 1u)) >> 16;
    ub = (ub + 0x7FFFu + ((ub >> 16) & 1u)) >> 16;
    return ua | (ub << 16);
}

// ---------------- dense-linear body (shared) --------------------------------
// 32-node x 128-output tile, 256 threads, 2x8 micro-tile.
// xl output stored FP16 (halves the gat gather bytes); xr stays FP32.
template <int K>
__device__ __forceinline__ void lin_lr_body(int bid,
        const float* __restrict__ x,
        const float* __restrict__ Wl, const float* __restrict__ bl,
        const float* __restrict__ Wr, const float* __restrict__ br,
        __half* __restrict__ xl, float* __restrict__ xr, int n) {
    __shared__ float Ash[32][K + 4];
    __shared__ float Wsh[K][128];
    const int t = threadIdx.x;
    const int node0 = bid * 32;

    for (int idx = t; idx < 32 * (K / 4); idx += 256) {
        int m = idx / (K / 4), kq = idx % (K / 4);
        float4 v = make_float4(0.f, 0.f, 0.f, 0.f);
        if (node0 + m < n) v = ((const float4*)(x + (size_t)(node0 + m) * K))[kq];
        *(float4*)&Ash[m][kq * 4] = v;
    }
    for (int idx = t; idx < K * 32; idx += 256) {
        int k = idx / 32, j4 = idx % 32;
        float4 v = (j4 < 16) ? ((const float4*)(Wl + (size_t)k * 64))[j4]
                             : ((const float4*)(Wr + (size_t)k * 64))[j4 - 16];
        *(float4*)&Wsh[k][j4 * 4] = v;
    }
    __syncthreads();

    const int ty = t >> 4;
    const int tx = t & 15;
    f32x2 c0[4], c1[4];
#pragma unroll
    for (int j = 0; j < 4; j++) {
        c0[j].x = 0.f; c0[j].y = 0.f;
        c1[j].x = 0.f; c1[j].y = 0.f;
    }

#pragma unroll 4
    for (int k = 0; k < K; k++) {
        float a0 = Ash[ty * 2 + 0][k];
        float a1 = Ash[ty * 2 + 1][k];
        float4 w0 = *(const float4*)&Wsh[k][tx * 8];
        float4 w1 = *(const float4*)&Wsh[k][tx * 8 + 4];
        f32x2 wv0; wv0.x = w0.x; wv0.y = w0.y;
        f32x2 wv1; wv1.x = w0.z; wv1.y = w0.w;
        f32x2 wv2; wv2.x = w1.x; wv2.y = w1.y;
        f32x2 wv3; wv3.x = w1.z; wv3.y = w1.w;
        f32x2 a0s; a0s.x = a0; a0s.y = a0;
        f32x2 a1s; a1s.x = a1; a1s.y = a1;
        c0[0] = pkfma(a0s, wv0, c0[0]);
        c0[1] = pkfma(a0s, wv1, c0[1]);
        c0[2] = pkfma(a0s, wv2, c0[2]);
        c0[3] = pkfma(a0s, wv3, c0[3]);
        c1[0] = pkfma(a1s, wv0, c1[0]);
        c1[1] = pkfma(a1s, wv1, c1[1]);
        c1[2] = pkfma(a1s, wv2, c1[2]);
        c1[3] = pkfma(a1s, wv3, c1[3]);
    }

    const float* bsrc = (tx < 8) ? bl : br;
    int jb = (tx < 8) ? tx * 8 : (tx - 8) * 8;
    float4 b0 = ((const float4*)(bsrc + jb))[0];
    float4 b1 = ((const float4*)(bsrc + jb))[1];
#pragma unroll
    for (int m = 0; m < 2; m++) {
        int node = node0 + ty * 2 + m;
        if (node >= n) continue;
        const f32x2* cc = (m == 0) ? c0 : c1;
        float o0 = cc[0].x + b0.x, o1 = cc[0].y + b0.y;
        float o2 = cc[1].x + b0.z, o3 = cc[1].y + b0.w;
        float o4 = cc[2].x + b1.x, o5 = cc[2].y + b1.y;
        float o6 = cc[3].x + b1.z, o7 = cc[3].y + b1.w;
        if (tx < 8) {
            __half2 h0 = __floats2half2_rn(o0, o1);
            __half2 h1 = __floats2half2_rn(o2, o3);
            __half2 h2 = __floats2half2_rn(o4, o5);
            __half2 h3 = __floats2half2_rn(o6, o7);
            uint4 pk;
            pk.x = *(unsigned*)&h0; pk.y = *(unsigned*)&h1;
            pk.z = *(unsigned*)&h2; pk.w = *(unsigned*)&h3;
            *((uint4*)(xl + (size_t)node * 64 + jb)) = pk;
        } else {
            float4 f0 = make_float4(o0, o1, o2, o3);
            float4 f1 = make_float4(o4, o5, o6, o7);
            ((float4*)(xr + (size_t)node * 64 + jb))[0] = f0;
            ((float4*)(xr + (size_t)node * 64 + jb))[1] = f1;
        }
    }
}

// ---------------- K1: count + rank + scatter, single global read ------------
// One pass over {src,dst,ea}; records staged in LDS (rec, rank, bucket),
// then scattered straight from LDS after the cursor reserve. Per-edge
// atomics stay in LDS (R4: global per-edge atomics cost ~77 us).
// R11: NCH=512/Ec~3125 is the measured optimum — R10's NCH=1024 halved the
// per-bucket scatter granularity (~8 records/segment) and doubled cursor
// contention: +19 us. Do not shrink chunks further.
__global__ __launch_bounds__(512, 2)
void count_scatter(const int* __restrict__ srcr, const int* __restrict__ dstr,
                   const float* __restrict__ ea, int* __restrict__ cursor,
                   int2* __restrict__ inter, int E, int Ec, int NB, int cap) {
    __shared__ int2 recsh[3584];
    __shared__ unsigned short rksh[3584];
    __shared__ unsigned char bksh[3584];
    __shared__ int hist[256];
    __shared__ int colsh[256];
    const int blk = blockIdx.x;
    const int t = threadIdx.x;
    if (t < 256) hist[t] = 0;
    __syncthreads();
    const int s0 = blk * Ec, s1 = min(E, s0 + Ec);
    const int cnt = s1 - s0;
    for (int e = s0 + t; e < s1; e += 512) {
        int d = dstr[e];
        float2 v = ((const float2*)ea)[e];
        int2 r;
        r.x = srcr[e] | ((d & 255) << 24);
        r.y = (int)bf16pack(v.x, v.y);
        int li = e - s0;
        int bk = (unsigned)d >> 8;
        recsh[li] = r;
        bksh[li] = (unsigned char)bk;
        rksh[li] = (unsigned short)atomicAdd(&hist[bk], 1);
    }
    __syncthreads();
    if (t < NB) {
        int h = hist[t];
        colsh[t] = t * cap + (h ? atomicAdd(&cursor[t], h) : 0);
    }
    __syncthreads();
    for (int li = t; li < cnt; li += 512)
        inter[colsh[bksh[li]] + (int)rksh[li]] = recsh[li];
}

// ---------------- K2: per-bucket CSR finalize || lin1 -----------------------
// csr has only NB=196 blocks on 256 CUs; lin1 (no dependency on the CSR)
// fills the idle CUs so K2 costs ~max(csr, lin1) instead of csr + lin1.
__global__ __launch_bounds__(256, 2)
void fused_csr_lin1(const int2* __restrict__ inter, const int* __restrict__ cursor,
                    int2* __restrict__ rse, int2* __restrict__ edges,
                    int NB, int N, int cap,
                    const float* __restrict__ x,
                    const float* __restrict__ Wl, const float* __restrict__ bl,
                    const float* __restrict__ Wr, const float* __restrict__ br,
                    __half* __restrict__ xl, float* __restrict__ xr, int n) {
    if ((int)blockIdx.x >= NB) {
        lin_lr_body<DIN>(blockIdx.x - NB, x, Wl, bl, Wr, br, xl, xr, n);
        return;
    }
    __shared__ int sh[256];
    __shared__ int cur[256];
    const int b = blockIdx.x, t = threadIdx.x;
    const int bstart = b * cap;
    const int bend = bstart + cursor[b];

    sh[t] = 0;
    __syncthreads();
    for (int pos = bstart + t; pos < bend; pos += 256)
        atomicAdd(&sh[((unsigned)inter[pos].x) >> 24], 1);
    __syncthreads();
    int cnt_v = sh[t];
    __syncthreads();
    sh[t] = cnt_v;
    __syncthreads();
    for (int off = 1; off < 256; off <<= 1) {
        int xv = (t >= off) ? sh[t - off] : 0;
        __syncthreads();
        sh[t] += xv;
        __syncthreads();
    }
    {
        int excl = sh[t] - cnt_v;
        cur[t] = excl;
        int myrs = bstart + excl;
        int node = b * 256 + t;
        if (node < N) rse[node] = make_int2(myrs, myrs + cnt_v);
    }
    __syncthreads();
    for (int pos = bstart + t; pos < bend; pos += 256) {
        int2 r = inter[pos];
        int k = atomicAdd(&cur[((unsigned)r.x) >> 24], 1);
        r.x &= 0x00FFFFFF;                      // strip dst byte for gat
        edges[bstart + k] = r;
    }
    // zero the gap so gat prefetches past rse[] read {src=0, ea=0} records
    int zend = (b + 1) * cap + ((b == NB - 1) ? 64 : 0);
    for (int pos = bend + t; pos < zend; pos += 256)
        edges[pos] = make_int2(0, 0);
}

// ---------------- GATv2 edge phase ------------------------------------------
// R0/R1 loop structure: full 128-B row gather, 8 edges/iter, 1-deep
// pipeline, packed f32 math, inline self-loop mean. FUSE_LIN2: W2 staged in
// LDS once per 512-thr block, h broadcast via v_readlane.
template <int H, int C, bool FUSE_HEADS, bool FUSE_LIN2>
__global__ __launch_bounds__(512)
void gat_kernel(const __half* __restrict__ xl, const float* __restrict__ xr,
                const int2* __restrict__ rse,
                const int2* __restrict__ edges,
                const float* __restrict__ We, const float* __restrict__ att,
                const float* __restrict__ bias, float* __restrict__ hout,
                const float* __restrict__ w2l, const float* __restrict__ b2l,
                const float* __restrict__ w2r, const float* __restrict__ b2r,
                __half* __restrict__ xl2o, float* __restrict__ xr2o,
                const float* __restrict__ wa, const float* __restrict__ ba,
                const float* __restrict__ wc, const float* __restrict__ bc,
                const float* __restrict__ ls, float* __restrict__ pout,
                int n) {
    constexpr int LPH = C / 4;
    __shared__ float W2sh[FUSE_LIN2 ? 64 * 128 : 4];
    if constexpr (FUSE_LIN2) {
        // stage W2 (cols 0-63 = w2l, 64-127 = w2r) before any wave returns
        for (int idx = threadIdx.x; idx < 64 * 32; idx += (int)blockDim.x) {
            int k = idx >> 5, j4 = idx & 31;
            float4 v = (j4 < 16) ? ((const float4*)(w2l + (size_t)k * 64))[j4]
                                 : ((const float4*)(w2r + (size_t)k * 64))[j4 - 16];
            *(float4*)&W2sh[k * 128 + j4 * 4] = v;
        }
        __syncthreads();
    }
    if (FUSE_HEADS && blockIdx.x == 0 && threadIdx.x < 2)
        pout[(size_t)n * 2 + threadIdx.x] = expf(ls[threadIdx.x]);
    const int lane = threadIdx.x & 63;
    const int wid = (blockIdx.x * blockDim.x + threadIdx.x) >> 6;
    if (wid >= n) return;
    const int i = wid;
    const int g = lane >> 4;
    const int q = lane & 15;

    const uint2* xlh = (const uint2*)xl;      // 4 halfs per uint2; row = 16
    const float4 xri4 = ((const float4*)(xr + (size_t)i * 64))[q];
    const float4 we04 = ((const float4*)We)[q];
    const float4 we14 = ((const float4*)(We + 64))[q];
    const float4 av4 = ((const float4*)att)[q];
    const float LOG2E = 1.4426950408889634f;
    f32x2 xrlo; xrlo.x = xri4.x; xrlo.y = xri4.y;
    f32x2 xrhi; xrhi.x = xri4.z; xrhi.y = xri4.w;
    f32x2 we0lo; we0lo.x = we04.x; we0lo.y = we04.y;
    f32x2 we0hi; we0hi.x = we04.z; we0hi.y = we04.w;
    f32x2 we1lo; we1lo.x = we14.x; we1lo.y = we14.y;
    f32x2 we1hi; we1hi.x = we14.z; we1hi.y = we14.w;
    f32x2 avlo; avlo.x = av4.x * LOG2E; avlo.y = av4.y * LOG2E;
    f32x2 avhi; avhi.x = av4.z * LOG2E; avhi.y = av4.w * LOG2E;

    auto h4lo = [](uint2 h) -> f32x2 {
        float2 a = __half22float2(*(__half2*)&h.x);
        f32x2 r; r.x = a.x; r.y = a.y; return r;
    };
    auto h4hi = [](uint2 h) -> f32x2 {
        float2 b = __half22float2(*(__half2*)&h.y);
        f32x2 r; r.x = b.x; r.y = b.y; return r;
    };
    // leaky_relu(xh + ea0*we0 + ea1*we1 + xri) . att   (att pre-scaled LOG2E)
    auto logit_of = [&](f32x2 xlo, f32x2 xhi, float ea0, float ea1) -> float {
        f32x2 e0; e0.x = ea0; e0.y = ea0;
        f32x2 e1; e1.x = ea1; e1.y = ea1;
        f32x2 ylo = xlo + pkfma(e0, we0lo, pkfma(e1, we1lo, xrlo));
        f32x2 yhi = xhi + pkfma(e0, we0hi, pkfma(e1, we1hi, xrhi));
        ylo = pkmax(ylo, ylo * 0.2f);
        yhi = pkmax(yhi, yhi * 0.2f);
        f32x2 l2 = pkfma(ylo, avlo, yhi * avhi);
        return l2.x + l2.y;
    };

    float den = 0.f;
    float sea0 = 0.f, sea1 = 0.f;   // inline ea sums for self-loop mean
    f32x2 aclo; aclo.x = 0.f; aclo.y = 0.f;
    f32x2 achi; achi.x = 0.f; achi.y = 0.f;

    const int2 se = rse[i];
    const int e0 = se.x, e1 = se.y;
    const int r = (e1 - e0) & 7;

    // ---- masked head: the (deg mod 8) ragged edges, done FIRST ----
    if (r) {
        int2 h0 = edges[e0 + g];
        int2 h1 = edges[e0 + 4 + g];
        uint2 u0 = xlh[(h0.x << 4) + q];
        uint2 u1 = xlh[(h1.x << 4) + q];
        f32x2 x0lo = h4lo(u0), x0hi = h4hi(u0);
        f32x2 x1lo = h4lo(u1), x1hi = h4hi(u1);
        const bool v0 = g < r;
        const bool v1 = (4 + g) < r;
        float ea00 = v0 ? __int_as_float(h0.y << 16) : 0.f;
        float ea01 = v0 ? __int_as_float(h0.y & 0xFFFF0000) : 0.f;
        float ea10 = v1 ? __int_as_float(h1.y << 16) : 0.f;
        float ea11 = v1 ? __int_as_float(h1.y & 0xFFFF0000) : 0.f;
        sea0 += ea00 + ea10;
        sea1 += ea01 + ea11;
        float l0 = logit_of(x0lo, x0hi, ea00, ea01);
        float l1 = logit_of(x1lo, x1hi, ea10, ea11);
#pragma unroll
        for (int m = 1; m < LPH; m <<= 1) {
            l0 += __shfl_xor(l0, m, 64);
            l1 += __shfl_xor(l1, m, 64);
        }
        float p0 = v0 ? exp2f(l0) : 0.f;
        float p1 = v1 ? exp2f(l1) : 0.f;
        den += p0 + p1;
        f32x2 p0s; p0s.x = p0; p0s.y = p0;
        f32x2 p1s; p1s.x = p1; p1s.y = p1;
        aclo = pkfma(p0s, x0lo, pkfma(p1s, x1lo, aclo));
        achi = pkfma(p0s, x0hi, pkfma(p1s, x1hi, achi));
    }

    // ---- mask-free main loop (multiple of 8 edges), 1-deep pipeline ----
    const int em = e0 + r;
    int2 rn0 = edges[em + g];
    int2 rn1 = edges[em + 4 + g];
    uint2 xpn0 = xlh[(rn0.x << 4) + q];
    uint2 xpn1 = xlh[(rn1.x << 4) + q];

    for (int eb = em; eb < e1; eb += 8) {
        int2 r0 = rn0, r1 = rn1;
        f32x2 x0lo = h4lo(xpn0), x0hi = h4hi(xpn0);
        f32x2 x1lo = h4lo(xpn1), x1hi = h4hi(xpn1);
        rn0 = edges[eb + 8 + g];
        rn1 = edges[eb + 12 + g];
        xpn0 = xlh[(rn0.x << 4) + q];
        xpn1 = xlh[(rn1.x << 4) + q];

        float ea00 = __int_as_float(r0.y << 16);
        float ea01 = __int_as_float(r0.y & 0xFFFF0000);
        float ea10 = __int_as_float(r1.y << 16);
        float ea11 = __int_as_float(r1.y & 0xFFFF0000);
        sea0 += ea00 + ea10;
        sea1 += ea01 + ea11;

        float l0 = logit_of(x0lo, x0hi, ea00, ea01);
        float l1 = logit_of(x1lo, x1hi, ea10, ea11);
#pragma unroll
        for (int m = 1; m < LPH; m <<= 1) {
            l0 += __shfl_xor(l0, m, 64);
            l1 += __shfl_xor(l1, m, 64);
        }
        float p0 = exp2f(l0);
        float p1 = exp2f(l1);
        den += p0 + p1;
        f32x2 p0s; p0s.x = p0; p0s.y = p0;
        f32x2 p1s; p1s.x = p1; p1s.y = p1;
        aclo = pkfma(p0s, x0lo, pkfma(p1s, x1lo, aclo));
        achi = pkfma(p0s, x0hi, pkfma(p1s, x1hi, achi));
    }

    float a0 = aclo.x, a1 = aclo.y, a2 = achi.x, a3 = achi.y;

    // merge the 4 edge-slot groups — pure adds (sea folded in here too)
#pragma unroll
    for (int m = 16; m < 64; m <<= 1) {
        den += __shfl_xor(den, m, 64);
        a0 += __shfl_xor(a0, m, 64);
        a1 += __shfl_xor(a1, m, 64);
        a2 += __shfl_xor(a2, m, 64);
        a3 += __shfl_xor(a3, m, 64);
        sea0 += __shfl_xor(sea0, m, 64);
        sea1 += __shfl_xor(sea1, m, 64);
    }

    // self-loop: mean attr computed inline (deg = e1-e0; 0-deg -> 0 mean,
    // matching reference's sums/max(cnt,1))
    const int cnt_i = e1 - e0;
    const float invc = cnt_i ? 1.0f / (float)cnt_i : 0.f;
    const float lamx = sea0 * invc;
    const float lamy = sea1 * invc;
    uint2 us = xlh[(i << 4) + q];
    f32x2 xslo = h4lo(us), xshi = h4hi(us);
    {
        float l = logit_of(xslo, xshi, lamx, lamy);
#pragma unroll
        for (int m = 1; m < LPH; m <<= 1) l += __shfl_xor(l, m, 64);
        float p = exp2f(l);
        den += p;
        a0 = fmaf(p, xslo.x, a0);
        a1 = fmaf(p, xslo.y, a1);
        a2 = fmaf(p, xshi.x, a2);
        a3 = fmaf(p, xshi.y, a3);
    }

    float rd = 1.0f / den;
    const float4 bv = ((const float4*)bias)[q];
    float4 o;
    o.x = fmaxf(fmaf(a0, rd, bv.x), 0.f);
    o.y = fmaxf(fmaf(a1, rd, bv.y), 0.f);
    o.z = fmaxf(fmaf(a2, rd, bv.z), 0.f);
    o.w = fmaxf(fmaf(a3, rd, bv.w), 0.f);
    // o (= post-ReLU h-row fragment for features 4q..4q+3) is identical in
    // all 4 lane-groups: every input to it was group-invariant.

    if constexpr (FUSE_LIN2) {
        // lin2: out[j] = sum_k h[k]*W2[k][j] + b2[j]; lane owns cols 2*lane,
        // 2*lane+1 (cols<64 -> xl2 via w2l, cols>=64 -> xr2 via w2r).
        const int hl = lane & 31;
        const bool isl = lane < 32;
        f32x2 s; s.x = 0.f; s.y = 0.f;
#pragma unroll
        for (int k = 0; k < 64; k++) {
            float comp = ((k & 3) == 0) ? o.x : ((k & 3) == 1) ? o.y
                       : ((k & 3) == 2) ? o.z : o.w;
            float hk = __uint_as_float(
                __builtin_amdgcn_readlane(__float_as_uint(comp), k >> 2));
            f32x2 hs; hs.x = hk; hs.y = hk;
            f32x2 wv = *(const f32x2*)&W2sh[k * 128 + 2 * lane];
            s = pkfma(hs, wv, s);
        }
        const float* bsel = isl ? b2l : b2r;
        s.x += bsel[2 * hl];
        s.y += bsel[2 * hl + 1];
        if (isl) {
            __half2 hx = __floats2half2_rn(s.x, s.y);
            *(unsigned*)(xl2o + (size_t)i * 64 + 2 * hl) = *(unsigned*)&hx;
        } else {
            ((float2*)(xr2o + (size_t)i * 64))[hl] = make_float2(s.x, s.y);
        }
    } else if (!FUSE_HEADS) {
        if (g == 0) ((float4*)(hout + (size_t)i * 64))[q] = o;
    } else {
        float4 wa01 = ((const float4*)wa)[q * 2];
        float4 wa23 = ((const float4*)wa)[q * 2 + 1];
        float4 wcv  = ((const float4*)wc)[q];
        float d0 = o.x * wa01.x + o.y * wa01.z + o.z * wa23.x + o.w * wa23.z;
        float d1 = o.x * wa01.y + o.y * wa01.w + o.z * wa23.y + o.w * wa23.w;
        float d2 = o.x * wcv.x + o.y * wcv.y + o.z * wcv.z + o.w * wcv.w;
#pragma unroll
        for (int m = 1; m < 16; m <<= 1) {
            d0 += __shfl_xor(d0, m, 64);
            d1 += __shfl_xor(d1, m, 64);
            d2 += __shfl_xor(d2, m, 64);
        }
        if (lane == 0) {
            pout[(size_t)i * 2 + 0] = tanhf(d0 + ba[0]);
            pout[(size_t)i * 2 + 1] = tanhf(d1 + ba[1]);
            pout[(size_t)n * 2 + 2 + i] = d2 + bc[0];
        }
    }
}

// ---------------- launch ---------------------------------------------------

extern "C" void kernel_launch(void* const* d_in, const int* in_sizes, int n_in,
                              void* d_out, int out_size, void* d_ws, size_t ws_size,
                              hipStream_t stream) {
    const float* x    = (const float*)d_in[0];
    const int*   ei   = (const int*)  d_in[1];
    const float* ea   = (const float*)d_in[2];
    const float* w1l  = (const float*)d_in[3];
    const float* b1l  = (const float*)d_in[4];
    const float* w1r  = (const float*)d_in[5];
    const float* b1r  = (const float*)d_in[6];
    const float* w1e  = (const float*)d_in[7];
    const float* att1 = (const float*)d_in[8];
    const float* bias1= (const float*)d_in[9];
    const float* w2l  = (const float*)d_in[10];
    const float* b2l  = (const float*)d_in[11];
    const float* w2r  = (const float*)d_in[12];
    const float* b2r  = (const float*)d_in[13];
    const float* w2e  = (const float*)d_in[14];
    const float* att2 = (const float*)d_in[15];
    const float* bias2= (const float*)d_in[16];
    const float* wa   = (const float*)d_in[17];
    const float* ba   = (const float*)d_in[18];
    const float* wc   = (const float*)d_in[19];
    const float* bc   = (const float*)d_in[20];
    const float* ls   = (const float*)d_in[21];

    const int N = in_sizes[0] / DIN;
    const int E = in_sizes[2] / 2;
    const int* srcr = ei;
    const int* dstr = ei + E;

    const int NB = (N + 255) >> 8;           // node buckets (196)
    const int NCH = 512;                     // edge chunks (rec LDS <= 3584)
    const int Ec = (E + NCH - 1) / NCH;      // edges per chunk (~3125)
    int cap = (E + NB - 1) / NB;             // bucket capacity, 1.25x mean
    cap = ((cap + cap / 4) + 63) & ~63;

    char* p = (char*)d_ws;
    auto alloc = [&](size_t bytes) -> void* {
        void* r = (void*)p;
        p += (bytes + 255) & ~(size_t)255;
        return r;
    };
    int*    cursor = (int*)   alloc(256 * 4);
    int2*   rse    = (int2*)  alloc((size_t)N * 8);
    int2*   edges  = (int2*)  alloc(((size_t)NB * cap + 64) * 8);
    __half* xl     = (__half*)alloc((size_t)N * F1 * 2);
    float*  xr     = (float*) alloc((size_t)N * F1 * 4);
    // layer-2 feature buffers (fused gat1+lin2 writes these; must NOT alias
    // xl/xr which gat1 is still gathering from)
    __half* xl2    = (__half*)alloc((size_t)N * F2 * 2);
    float*  xr2    = (float*) alloc((size_t)N * F2 * 4);
    // inter (NB*cap*8 ~= 16 MB) aliases xl2+xr2 (19.2 MB); consumed by the
    // csr blocks of fused_csr_lin1 before gat1 (which writes xl2/xr2) runs.
    int2* inter = (int2*)xl2;
    (void)ws_size; (void)n_in; (void)out_size;

    hipMemsetAsync(cursor, 0, 256 * 4, stream);

    const int TB = 256;
    int gridGemm = (N + 31) / 32;
    int gridW1 = (N + 7) / 8;       // gat1: 512-thr blocks, 8 nodes each
    int gridW2 = (N + 3) / 4;       // gat2: 256-thr blocks, 4 nodes each

    count_scatter<<<NCH, 512, 0, stream>>>(srcr, dstr, ea, cursor, inter,
                                           E, Ec, NB, cap);
    fused_csr_lin1<<<NB + gridGemm, TB, 0, stream>>>(
        inter, cursor, rse, edges, NB, N, cap,
        x, w1l, b1l, w1r, b1r, xl, xr, N);

    // gat layer 1 with lin2 fused into the epilogue (LDS-staged W2)
    gat_kernel<4, 16, false, true><<<gridW1, 512, 0, stream>>>(
        xl, xr, rse, edges, w1e, att1, bias1, nullptr,
        w2l, b2l, w2r, b2r, xl2, xr2,
        nullptr, nullptr, nullptr, nullptr, nullptr, nullptr, N);

    // gat layer 2 with actor/critic head fused
    gat_kernel<2, 32, true, false><<<gridW2, TB, 0, stream>>>(
        xl2, xr2, rse, edges, w2e, att2, bias2, nullptr,
        nullptr, nullptr, nullptr, nullptr, nullptr, nullptr,
        wa, ba, wc, bc, ls, (float*)d_out, N);
}